// Round 4
// baseline (1270.250 us; speedup 1.0000x reference)
//
#include <hip/hip_runtime.h>
#include <hip/hip_bf16.h>

typedef __hip_bfloat16 bf16;
typedef float f32x2 __attribute__((ext_vector_type(2)));

#define NB_B 4
#define N 20000
#define E 640000
#define F 64
#define HC 128   // conv1 heads*ch
#define ED 16
#define CH 16
#define NT 32    // nodes per tile in node-transform kernels

__device__ __forceinline__ float clampf(float v, float lo, float hi){ return fminf(fmaxf(v, lo), hi); }
__device__ __forceinline__ float ldv(const float* p, size_t i){ return p[i]; }
__device__ __forceinline__ float ldv(const bf16*  p, size_t i){ return __bfloat162float(p[i]); }
__device__ __forceinline__ void  stv(float* p, size_t i, float v){ p[i] = v; }
__device__ __forceinline__ void  stv(bf16*  p, size_t i, float v){ p[i] = __float2bfloat16(v); }
__device__ __forceinline__ unsigned short tobf(float v){ bf16 b = __float2bfloat16(v); return *(unsigned short*)&b; }
__device__ __forceinline__ float unpl(unsigned u){ return __uint_as_float(u << 16); }
__device__ __forceinline__ float unph(unsigned u){ return __uint_as_float(u & 0xffff0000u); }
__device__ __forceinline__ f32x2 mk2(float a, float b){ f32x2 r; r.x = a; r.y = b; return r; }
__device__ __forceinline__ int rfl(int v){ return __builtin_amdgcn_readfirstlane(v); }

#define L2E 1.44269504f

// packed f32 FMA: d += a*b elementwise on (lo,hi) pairs. Forces v_pk_fma_f32 —
// the compiler was scalarizing f32x2 arithmetic (2x VALU issue).
__device__ __forceinline__ void pkfma(f32x2& d, f32x2 a, f32x2 b){
  asm("v_pk_fma_f32 %0, %1, %2, %0" : "+v"(d) : "v"(a), "v"(b));
}
// keep a value materialized in VGPRs (defeat rematerialization of loop-invariant loads)
__device__ __forceinline__ void pin(f32x2& v){ asm volatile("" : "+v"(v)); }
__device__ __forceinline__ void pin(float& v){ asm volatile("" : "+v"(v)); }

// 16-lane (DPP row) all-reduce sum: pure VALU (row_ror butterfly 8,4,2,1).
__device__ __forceinline__ float rsum16(float x){
  x += __int_as_float(__builtin_amdgcn_update_dpp(0, __float_as_int(x), 0x128, 0xf, 0xf, true));
  x += __int_as_float(__builtin_amdgcn_update_dpp(0, __float_as_int(x), 0x124, 0xf, 0xf, true));
  x += __int_as_float(__builtin_amdgcn_update_dpp(0, __float_as_int(x), 0x122, 0xf, 0xf, true));
  x += __int_as_float(__builtin_amdgcn_update_dpp(0, __float_as_int(x), 0x121, 0xf, 0xf, true));
  return x;
}
__device__ __forceinline__ float leaky(float g){
  float a = __uint_as_float(__float_as_uint(g) & 0x7fffffffu);   // |g|
  return fmaf(0.4f, a, 0.6f*g);                                  // max(g,0)+0.2min(g,0)
}

// ---------------- dtype detector: f32 inputs (flag=1) vs bf16 (flag=0) ----------------
__global__ __launch_bounds__(256) void k_detect(const unsigned short* __restrict__ xu, int* __restrict__ flag){
  __shared__ int cnt[256];
  int tid = threadIdx.x;
  unsigned short lo = xu[2*tid];
  bf16 h = *(const bf16*)&lo;
  float v = fabsf(__bfloat162float(h));
  cnt[tid] = (v > 1e4f || (v != 0.f && v < 1e-4f)) ? 1 : 0;
  __syncthreads();
  for (int s=128; s>0; s>>=1){ if (tid<s) cnt[tid]+=cnt[tid+s]; __syncthreads(); }
  if (tid==0) *flag = (cnt[0] > 64) ? 1 : 0;
}

// ---------------- CSR build: histogram -> scan -> scatter(+ea reorder) ----------------
__global__ __launch_bounds__(256) void k_hist(const int* __restrict__ ei, int* __restrict__ cnt, int b0){
  int z = blockIdx.z, b = b0 + z;
  int e = blockIdx.x*256 + threadIdx.x;
  int d = ei[((size_t)b*2+1)*E + e];
  atomicAdd(&cnt[z*N + d], 1);
}

__global__ __launch_bounds__(256) void k_scan(const int* __restrict__ cnt, int* __restrict__ rowptr,
                                              int* __restrict__ cursor){
  int z = blockIdx.z, tid = threadIdx.x;
  const int* c = cnt + (size_t)z*N;
  int* rp = rowptr + (size_t)z*(N+1);
  int* cu = cursor + (size_t)z*N;
  const int CHK = (N + 255)/256;
  int lo = tid*CHK; int hi = lo + CHK; if (hi > N) hi = N; if (lo > N) lo = N;
  int s = 0;
  for (int i=lo;i<hi;i++) s += c[i];
  __shared__ int buf[256];
  buf[tid] = s; __syncthreads();
  for (int off=1; off<256; off<<=1){
    int t = (tid>=off) ? buf[tid-off] : 0;
    __syncthreads();
    buf[tid] += t;
    __syncthreads();
  }
  int run = buf[tid] - s;         // exclusive prefix
  for (int i=lo;i<hi;i++){ int v=c[i]; rp[i]=run; cu[i]=run; run += v; }
  if (tid==255) rp[N] = run;
}

// scatter: write src index + copy edge attrs into CSR order (f32, numerically identical).
template<typename T>
__device__ __forceinline__ void scatter_body(const int* ei, int* cursor, int* csr,
                                             const T* ea, float* eacsr, int b0){
  int z = blockIdx.z, b = b0 + z;
  int e = blockIdx.x*256 + threadIdx.x;
  int s = ei[((size_t)b*2+0)*E + e];
  int d = ei[((size_t)b*2+1)*E + e];
  int pos = atomicAdd(&cursor[z*N + d], 1);
  csr[(size_t)z*E + pos] = s;
  float4* dst = (float4*)(eacsr + ((size_t)z*E + pos)*ED);
  const T* sp = ea + ((size_t)b*E + e)*ED;
  #pragma unroll
  for (int g=0; g<4; g++){
    float4 t;
    t.x = ldv(sp, g*4+0); t.y = ldv(sp, g*4+1); t.z = ldv(sp, g*4+2); t.w = ldv(sp, g*4+3);
    dst[g] = t;
  }
}
__global__ __launch_bounds__(256) void k_scatter(const int* ei, int* cursor, int* csr,
    const void* ea, float* eacsr, const int* flag, int b0){
  if (*flag) scatter_body(ei, cursor, csr, (const float*)ea, eacsr, b0);
  else       scatter_body(ei, cursor, csr, (const bf16*) ea, eacsr, b0);
}

// ---------------- conv1 node transform: 32-node tile, writes packed bf16 directly ----------------
template<typename T>
__device__ __forceinline__ void node1_body(const T* x, const T* Wl, const T* Wr,
                                           unsigned* xl1p, unsigned* xr1p, int b0,
                                           float (*xs)[F+4]){
  int z = blockIdx.z, b = b0 + z;
  int node0 = blockIdx.x*NT;
  for (int i=threadIdx.x; i<NT*F; i+=256){
    int n = i>>6, k = i&63;
    xs[n][k] = ldv(x, ((size_t)b*N + node0 + n)*F + k);
  }
  __syncthreads();
  int mat = threadIdx.x >> 7, c = threadIdx.x & 127;
  const T* W = mat ? Wr : Wl;
  float acc[NT];
  #pragma unroll
  for (int n=0;n<NT;n++) acc[n]=0.f;
  for (int k=0;k<F;k+=4){
    float w0 = ldv(W, (size_t)(k+0)*HC + c);
    float w1 = ldv(W, (size_t)(k+1)*HC + c);
    float w2 = ldv(W, (size_t)(k+2)*HC + c);
    float w3 = ldv(W, (size_t)(k+3)*HC + c);
    #pragma unroll
    for (int n=0;n<NT;n++){
      float4 xv = *(const float4*)&xs[n][k];
      acc[n] += xv.x*w0 + xv.y*w1 + xv.z*w2 + xv.w*w3;
    }
  }
  unsigned short* outp = (unsigned short*)(mat ? xr1p : xl1p);
  int half = c>>6, cc = c&63;
  #pragma unroll
  for (int n=0;n<NT;n++){
    float v = clampf(acc[n], -1e4f, 1e4f);
    outp[(((size_t)z*N + node0 + n)*64 + cc)*2 + half] = tobf(v);
  }
}
__global__ __launch_bounds__(256) void k_node1(const void* x, const void* Wl, const void* Wr,
    unsigned* xl1p, unsigned* xr1p, const int* flag, int b0){
  __shared__ float xs[NT][F+4];
  if (*flag) node1_body((const float*)x,(const float*)Wl,(const float*)Wr,xl1p,xr1p,b0,xs);
  else       node1_body((const bf16*) x,(const bf16*) Wl,(const bf16*) Wr,xl1p,xr1p,b0,xs);
}

// ---------------- conv1 fused gather: wave-per-node, j-pair packed-f32 dot ----------------
// Per edge: ee-dot = 8 v_pk_fma (channel cL) + 8 (channel cH) over j-pairs loaded straight
// from eacsr as f32x2 — no operand broadcast needed. Weights pinned in VGPRs.
template<typename T>
__device__ __forceinline__ void gather1_body(const int* __restrict__ rowptr, const int* __restrict__ csr,
    const float* __restrict__ eacsr, const T* __restrict__ We, const T* __restrict__ att, const T* __restrict__ b1,
    const unsigned* __restrict__ xl1p, const unsigned* __restrict__ xr1p, float* __restrict__ hx, int b0){
  int z = blockIdx.z;
  int lane = threadIdx.x & 63;
  int node = rfl(blockIdx.x*4 + (threadIdx.x >> 6));
  int rs = rfl(rowptr[(size_t)z*(N+1) + node]);
  int re = rfl(rowptr[(size_t)z*(N+1) + node + 1]);
  // weights as j-pairs: wA[jp] = (We[2jp][lane], We[2jp+1][lane]); wB same for lane+64
  f32x2 wA[8], wB[8];
  #pragma unroll
  for (int jp=0;jp<8;jp++){
    wA[jp] = mk2(ldv(We,(size_t)(2*jp)*HC+lane),    ldv(We,(size_t)(2*jp+1)*HC+lane));
    wB[jp] = mk2(ldv(We,(size_t)(2*jp)*HC+lane+64), ldv(We,(size_t)(2*jp+1)*HC+lane+64));
    pin(wA[jp]); pin(wB[jp]);
  }
  float attL = ldv(att,(size_t)lane)*L2E, attH = ldv(att,(size_t)lane+64)*L2E;
  pin(attL); pin(attH);
  unsigned xru = xr1p[((size_t)z*N + node)*64 + lane];
  float xrL = unpl(xru), xrH = unph(xru);
  pin(xrL); pin(xrH);
  float accL=0.f, accH=0.f, denL=0.f, denH=0.f;
  const unsigned* __restrict__ xlp = xl1p + (size_t)z*N*64;
  const int* __restrict__ csrz = csr + (size_t)z*E + rs;
  const float* __restrict__ eaz = eacsr + ((size_t)z*E + rs)*ED;
  int deg = re - rs;
  if (deg > 0){
    int s0 = rfl(csrz[0]);
    int s1 = (deg>1) ? rfl(csrz[1]) : s0;
    unsigned xa = xlp[(size_t)(unsigned)s0*64 + lane];
    unsigned xb = xlp[(size_t)(unsigned)s1*64 + lane];
    for (int i=0;i<deg;i++){
      const f32x2* __restrict__ ep = (const f32x2*)(eaz + (size_t)i*ED);
      f32x2 p0=ep[0], p1=ep[1], p2=ep[2], p3=ep[3], p4=ep[4], p5=ep[5], p6=ep[6], p7=ep[7];
      unsigned xw = xa;
      xa = xb;
      if (i+2 < deg){
        int sn = rfl(csrz[i+2]);
        xb = xlp[(size_t)(unsigned)sn*64 + lane];
      }
      f32x2 dA = mk2(0.f,0.f), dB = mk2(0.f,0.f);
      pkfma(dA, wA[0], p0); pkfma(dB, wB[0], p0);
      pkfma(dA, wA[1], p1); pkfma(dB, wB[1], p1);
      pkfma(dA, wA[2], p2); pkfma(dB, wB[2], p2);
      pkfma(dA, wA[3], p3); pkfma(dB, wB[3], p3);
      pkfma(dA, wA[4], p4); pkfma(dB, wB[4], p4);
      pkfma(dA, wA[5], p5); pkfma(dB, wB[5], p5);
      pkfma(dA, wA[6], p6); pkfma(dB, wB[6], p6);
      pkfma(dA, wA[7], p7); pkfma(dB, wB[7], p7);
      float xlL = unpl(xw), xlH = unph(xw);
      float gL = (xlL + xrL) + (dA.x + dA.y);
      float gH = (xlH + xrH) + (dB.x + dB.y);
      float vL = rsum16(leaky(gL)*attL);
      float vH = rsum16(leaky(gH)*attH);
      float exL = exp2f(clampf(vL,-86.f,86.f));
      float exH = exp2f(clampf(vH,-86.f,86.f));
      denL += exL; denH += exH;
      accL = fmaf(exL, xlL, accL);
      accH = fmaf(exH, xlH, accH);
    }
  }
  float hL = accL/(denL + 1e-16f) + ldv(b1,(size_t)lane);
  float hH = accH/(denH + 1e-16f) + ldv(b1,(size_t)lane+64);
  hL = hL>0.f ? hL : expm1f(hL);
  hH = hH>0.f ? hH : expm1f(hH);
  hx[((size_t)z*N + node)*HC + lane]      = hL;
  hx[((size_t)z*N + node)*HC + lane + 64] = hH;
}
__global__ __launch_bounds__(256) void k_gather1(const int* __restrict__ rowptr, const int* __restrict__ csr,
    const float* __restrict__ eacsr,
    const void* We, const void* att, const void* b1,
    const unsigned* __restrict__ xl1p, const unsigned* __restrict__ xr1p, float* __restrict__ hx,
    const int* __restrict__ flag, int b0){
  if (*flag) gather1_body(rowptr,csr,eacsr,(const float*)We,(const float*)att,(const float*)b1,xl1p,xr1p,hx,b0);
  else       gather1_body(rowptr,csr,eacsr,(const bf16*) We,(const bf16*) att,(const bf16*) b1,xl1p,xr1p,hx,b0);
}

// ---------------- conv2/conv3 node transforms: 32-node tile, writes packed bf16 directly ----------------
template<typename T>
__device__ __forceinline__ void node2_body(const float* hx, const unsigned* xl1p,
    const T* W2l, const T* W2r, const T* W3l, const T* W3r,
    unsigned* xl23p, unsigned* xr23p, int b0,
    float (*hv)[HC+4], float (*sv)[HC+4]){
  int z = blockIdx.z;
  int node0 = blockIdx.x*NT;
  for (int i=threadIdx.x; i<NT*HC; i+=256){
    int n = i>>7, k = i&127;
    float h = hx[((size_t)z*N + node0 + n)*HC + k];
    unsigned wxl = xl1p[((size_t)z*N + node0 + n)*64 + (k&63)];
    float xv = (k<64) ? unpl(wxl) : unph(wxl);
    hv[n][k] = h;
    sv[n][k] = h + xv;                // hs = hx + skip(=xl1)
  }
  __syncthreads();
  int o = threadIdx.x & 63;
  int mat = o >> 4, c = o & 15;
  int g = threadIdx.x >> 6;
  const T* W = (mat==0)? W2l : (mat==1)? W2r : (mat==2)? W3l : W3r;
  float (*src)[HC+4] = (mat<2)? hv : sv;
  float acc[8];
  #pragma unroll
  for (int j=0;j<8;j++) acc[j]=0.f;
  for (int k=0;k<HC;k+=4){
    float w0 = ldv(W, (size_t)(k+0)*CH + c);
    float w1 = ldv(W, (size_t)(k+1)*CH + c);
    float w2 = ldv(W, (size_t)(k+2)*CH + c);
    float w3 = ldv(W, (size_t)(k+3)*CH + c);
    #pragma unroll
    for (int j=0;j<8;j++){
      float4 xv = *(const float4*)&src[g*8+j][k];
      acc[j] += xv.x*w0 + xv.y*w1 + xv.z*w2 + xv.w*w3;
    }
  }
  unsigned short* arr = (unsigned short*)((mat&1) ? xr23p : xl23p);
  int half = mat>>1;
  #pragma unroll
  for (int j=0;j<8;j++){
    float v = clampf(acc[j], -1e4f, 1e4f);
    arr[(((size_t)z*N + node0 + g*8 + j)*CH + c)*2 + half] = tobf(v);
  }
}
__global__ __launch_bounds__(256) void k_node2(const float* hx, const unsigned* xl1p,
    const void* W2l, const void* W2r, const void* W3l, const void* W3r,
    unsigned* xl23p, unsigned* xr23p, const int* flag, int b0){
  __shared__ float hv[NT][HC+4];
  __shared__ float sv[NT][HC+4];
  if (*flag) node2_body(hx,xl1p,(const float*)W2l,(const float*)W2r,(const float*)W3l,(const float*)W3r,xl23p,xr23p,b0,hv,sv);
  else       node2_body(hx,xl1p,(const bf16*) W2l,(const bf16*) W2r,(const bf16*) W3l,(const bf16*) W3r,xl23p,xr23p,b0,hv,sv);
}

// ---------------- conv2+conv3 fused gather + linear + LayerNorm + store ----------------
// Wave-per-node: 64 lanes = 16 channels x 4 edge-groups. j-pair pk dot per conv.
template<typename T>
__device__ __forceinline__ void gather23_body(const int* __restrict__ rowptr, const int* __restrict__ csr,
    const float* __restrict__ eacsr,
    const T* __restrict__ We2, const T* __restrict__ We3, const T* __restrict__ att2, const T* __restrict__ att3,
    const T* __restrict__ b2, const T* __restrict__ b3, const T* __restrict__ linW, const T* __restrict__ linb,
    const T* __restrict__ lng, const T* __restrict__ lnb,
    const unsigned* __restrict__ xl23p, const unsigned* __restrict__ xr23p,
    T* __restrict__ out, int b0){
  int z = blockIdx.z;
  int lane = threadIdx.x & 63;
  int g = lane >> 4, c = lane & 15;
  int node = rfl(blockIdx.x*4 + (threadIdx.x >> 6));
  int rs = rfl(rowptr[(size_t)z*(N+1) + node]);
  int re = rfl(rowptr[(size_t)z*(N+1) + node + 1]);
  int deg = re - rs;
  f32x2 w2[8], w3[8];
  #pragma unroll
  for (int jp=0;jp<8;jp++){
    w2[jp] = mk2(ldv(We2,(size_t)(2*jp)*CH+c), ldv(We2,(size_t)(2*jp+1)*CH+c));
    w3[jp] = mk2(ldv(We3,(size_t)(2*jp)*CH+c), ldv(We3,(size_t)(2*jp+1)*CH+c));
    pin(w2[jp]); pin(w3[jp]);
  }
  float att2c = ldv(att2,(size_t)c)*L2E, att3c = ldv(att3,(size_t)c)*L2E;
  pin(att2c); pin(att3c);
  unsigned xru = xr23p[((size_t)z*N + node)*CH + c];
  float xr2v = unpl(xru), xr3v = unph(xru);
  pin(xr2v); pin(xr3v);
  float acc2=0.f, acc3=0.f, den2=0.f, den3=0.f;
  const unsigned* __restrict__ xlp = xl23p + (size_t)z*N*CH;
  const int* __restrict__ csrz = csr + (size_t)z*E + rs;
  const float* __restrict__ eaz = eacsr + ((size_t)z*E + rs)*ED;
  if (deg > 0){
    int idx0 = (g < deg) ? g : deg-1;
    int s = csrz[idx0];
    unsigned xw = xlp[(size_t)(unsigned)s*CH + c];
    const f32x2* p0 = (const f32x2*)(eaz + (size_t)idx0*ED);
    f32x2 e0=p0[0],e1=p0[1],e2=p0[2],e3=p0[3],e4=p0[4],e5=p0[5],e6=p0[6],e7=p0[7];
    for (int i=0;i<deg;i+=4){
      bool act = (i + g) < deg;
      unsigned xcur = xw;
      f32x2 q0=e0,q1=e1,q2=e2,q3=e3,q4=e4,q5=e5,q6=e6,q7=e7;
      if (i+4 < deg){                                  // prefetch next step
        int ii = i + 4 + g;
        int idx = (ii < deg) ? ii : deg-1;
        int s2 = csrz[idx];
        xw = xlp[(size_t)(unsigned)s2*CH + c];
        const f32x2* p2 = (const f32x2*)(eaz + (size_t)idx*ED);
        e0=p2[0];e1=p2[1];e2=p2[2];e3=p2[3];e4=p2[4];e5=p2[5];e6=p2[6];e7=p2[7];
      }
      f32x2 d2 = mk2(0.f,0.f), d3 = mk2(0.f,0.f);
      pkfma(d2, w2[0], q0); pkfma(d3, w3[0], q0);
      pkfma(d2, w2[1], q1); pkfma(d3, w3[1], q1);
      pkfma(d2, w2[2], q2); pkfma(d3, w3[2], q2);
      pkfma(d2, w2[3], q3); pkfma(d3, w3[3], q3);
      pkfma(d2, w2[4], q4); pkfma(d3, w3[4], q4);
      pkfma(d2, w2[5], q5); pkfma(d3, w3[5], q5);
      pkfma(d2, w2[6], q6); pkfma(d3, w3[6], q6);
      pkfma(d2, w2[7], q7); pkfma(d3, w3[7], q7);
      float xl2v = unpl(xcur), xl3v = unph(xcur);
      float g2 = (xl2v + xr2v) + (d2.x + d2.y);
      float g3 = (xl3v + xr3v) + (d3.x + d3.y);
      float v2 = rsum16(leaky(g2)*att2c);
      float v3 = rsum16(leaky(g3)*att3c);
      float ex2 = exp2f(clampf(v2,-86.f,86.f));
      float ex3 = exp2f(clampf(v3,-86.f,86.f));
      if (!act){ ex2 = 0.f; ex3 = 0.f; }
      den2 += ex2; den3 += ex3;
      acc2 = fmaf(ex2, xl2v, acc2);
      acc3 = fmaf(ex3, xl3v, acc3);
    }
  }
  // combine group partials (lanes {c, 16+c, 32+c, 48+c})
  acc2 += __shfl_xor(acc2, 16); acc2 += __shfl_xor(acc2, 32);
  acc3 += __shfl_xor(acc3, 16); acc3 += __shfl_xor(acc3, 32);
  den2 += __shfl_xor(den2, 16); den2 += __shfl_xor(den2, 32);
  den3 += __shfl_xor(den3, 16); den3 += __shfl_xor(den3, 32);
  float x1 = acc2/(den2 + 1e-16f) + ldv(b2,(size_t)c);   // conv2 output
  float x3 = acc3/(den3 + 1e-16f) + ldv(b3,(size_t)c);   // skip-conv output
  float x2 = 0.f;
  #pragma unroll
  for (int j=0;j<16;j++) x2 += __shfl(x3, j, 16) * ldv(linW, (size_t)c*16 + j);
  x2 += ldv(linb,(size_t)c);
  float y = clampf(x1, -1e6f, 1e6f) + clampf(x2, -1e6f, 1e6f);
  float mu = rsum16(y)*(1.f/16.f);
  float dv = y - mu;
  float var = rsum16(dv*dv)*(1.f/16.f);
  float o = dv*rsqrtf(var + 1e-5f)*ldv(lng,(size_t)c) + ldv(lnb,(size_t)c);
  if (lane < 16) stv(out, ((size_t)(b0+z)*N + node)*16 + c, o);
}
__global__ __launch_bounds__(256) void k_gather23(const int* __restrict__ rowptr, const int* __restrict__ csr,
    const float* __restrict__ eacsr,
    const void* We2, const void* We3, const void* att2, const void* att3,
    const void* b2, const void* b3, const void* linW, const void* linb, const void* lng, const void* lnb,
    const unsigned* __restrict__ xl23p, const unsigned* __restrict__ xr23p,
    void* out, const int* __restrict__ flag, int b0){
  if (*flag) gather23_body(rowptr,csr,eacsr,(const float*)We2,(const float*)We3,(const float*)att2,(const float*)att3,
                           (const float*)b2,(const float*)b3,(const float*)linW,(const float*)linb,(const float*)lng,(const float*)lnb,
                           xl23p,xr23p,(float*)out,b0);
  else       gather23_body(rowptr,csr,eacsr,(const bf16*) We2,(const bf16*) We3,(const bf16*) att2,(const bf16*) att3,
                           (const bf16*) b2,(const bf16*) b3,(const bf16*) linW,(const bf16*) linb,(const bf16*) lng,(const bf16*) lnb,
                           xl23p,xr23p,(bf16*) out,b0);
}

// ---------------- workspace layout ----------------
struct WSP {
  int* flag;
  int *cnt, *cursor, *rowptr; int* csr;
  float *eacsr, *hx;
  unsigned *xl1p,*xr1p,*xl23p,*xr23p;
  size_t total;
};
static WSP mkws(char* base, int nb){
  WSP w; size_t off = 0;
  auto A = [&](size_t bytes)->char*{ char* p = base ? base + off : (char*)0; off = (off + bytes + 255) & ~(size_t)255; return p; };
  w.flag   = (int*)     A(256);
  w.cnt    = (int*)     A((size_t)nb*N*4);
  w.cursor = (int*)     A((size_t)nb*N*4);
  w.rowptr = (int*)     A((size_t)nb*(N+1)*4);
  w.csr    = (int*)     A((size_t)nb*E*4);
  w.eacsr  = (float*)   A((size_t)nb*E*ED*4);
  w.hx     = (float*)   A((size_t)nb*N*HC*4);
  w.xl1p   = (unsigned*)A((size_t)nb*N*64*4);
  w.xr1p   = (unsigned*)A((size_t)nb*N*64*4);
  w.xl23p  = (unsigned*)A((size_t)nb*N*CH*4);
  w.xr23p  = (unsigned*)A((size_t)nb*N*CH*4);
  w.total = off;
  return w;
}

extern "C" void kernel_launch(void* const* d_in, const int* in_sizes, int n_in,
                              void* d_out, int out_size, void* d_ws, size_t ws_size,
                              hipStream_t stream){
  const void* x    = d_in[0];
  const void* ea   = d_in[1];
  const int*  ei   = (const int*)d_in[2];
  const void* c1Wl = d_in[3], *c1Wr = d_in[4], *c1We = d_in[5];
  const void* c1att= d_in[6], *c1b  = d_in[7];
  const void* c2Wl = d_in[8], *c2Wr = d_in[9], *c2We = d_in[10];
  const void* c2att= d_in[11],*c2b  = d_in[12];
  const void* sWl  = d_in[13],*sWr  = d_in[14],*sWe  = d_in[15];
  const void* satt = d_in[16],*sb   = d_in[17];
  const void* linW = d_in[18],*linb = d_in[19];
  const void* lng  = d_in[20],*lnb  = d_in[21];

  auto run = [&](int b0, int nb){
    WSP w = mkws((char*)d_ws, nb);
    hipMemsetAsync(w.cnt, 0, (size_t)nb*N*4, stream);
    k_hist   <<<dim3(E/256,1,nb),   256,0,stream>>>(ei, w.cnt, b0);
    k_scan   <<<dim3(1,1,nb),       256,0,stream>>>(w.cnt, w.rowptr, w.cursor);
    k_scatter<<<dim3(E/256,1,nb),   256,0,stream>>>(ei, w.cursor, w.csr, ea, w.eacsr, w.flag, b0);
    // conv1
    k_node1  <<<dim3(N/NT,1,nb),    256,0,stream>>>(x, c1Wl, c1Wr, w.xl1p, w.xr1p, w.flag, b0);
    k_gather1<<<dim3(N/4,1,nb),     256,0,stream>>>(w.rowptr, w.csr, w.eacsr, c1We, c1att, c1b,
                                                    w.xl1p, w.xr1p, w.hx, w.flag, b0);
    // conv2 + skip-conv
    k_node2  <<<dim3(N/NT,1,nb),    256,0,stream>>>(w.hx, w.xl1p, c2Wl, c2Wr, sWl, sWr,
                                                    w.xl23p, w.xr23p, w.flag, b0);
    k_gather23<<<dim3(N/4,1,nb),    256,0,stream>>>(w.rowptr, w.csr, w.eacsr, c2We, sWe, c2att, satt,
                                                    c2b, sb, linW, linb, lng, lnb,
                                                    w.xl23p, w.xr23p, d_out, w.flag, b0);
  };

  {
    WSP w0 = mkws((char*)d_ws, 1);
    k_detect<<<1,256,0,stream>>>((const unsigned short*)x, w0.flag);
  }

  WSP probe = mkws((char*)0, NB_B);
  if (ws_size >= probe.total){
    run(0, NB_B);                          // single batched pass
  } else {
    for (int g=0; g<NB_B; ++g) run(g, 1);  // per-graph fallback
  }
}

// Round 5
// 1141.033 us; speedup vs baseline: 1.1132x; 1.1132x over previous
//
#include <hip/hip_runtime.h>
#include <hip/hip_bf16.h>

typedef __hip_bfloat16 bf16;
typedef float f32x2 __attribute__((ext_vector_type(2)));

#define NB_B 4
#define N 20000
#define E 640000
#define F 64
#define HC 128   // conv1 heads*ch
#define ED 16
#define CH 16
#define NT 32    // nodes per tile in node-transform kernels
#define TB2 16   // edge tile per slot, gather23

__device__ __forceinline__ float clampf(float v, float lo, float hi){ return fminf(fmaxf(v, lo), hi); }
__device__ __forceinline__ float ldv(const float* p, size_t i){ return p[i]; }
__device__ __forceinline__ float ldv(const bf16*  p, size_t i){ return __bfloat162float(p[i]); }
__device__ __forceinline__ void  stv(float* p, size_t i, float v){ p[i] = v; }
__device__ __forceinline__ void  stv(bf16*  p, size_t i, float v){ p[i] = __float2bfloat16(v); }
__device__ __forceinline__ unsigned short tobf(float v){ bf16 b = __float2bfloat16(v); return *(unsigned short*)&b; }
__device__ __forceinline__ float unpl(unsigned u){ return __uint_as_float(u << 16); }
__device__ __forceinline__ float unph(unsigned u){ return __uint_as_float(u & 0xffff0000u); }
__device__ __forceinline__ f32x2 mk2(float a, float b){ f32x2 r; r.x = a; r.y = b; return r; }
__device__ __forceinline__ int rfl(int v){ return __builtin_amdgcn_readfirstlane(v); }

#define L2E 1.44269504f

// 16-lane (DPP row) all-reduce sum: pure VALU (row_ror butterfly 8,4,2,1).
__device__ __forceinline__ float rsum16(float x){
  x += __int_as_float(__builtin_amdgcn_update_dpp(0, __float_as_int(x), 0x128, 0xf, 0xf, true));
  x += __int_as_float(__builtin_amdgcn_update_dpp(0, __float_as_int(x), 0x124, 0xf, 0xf, true));
  x += __int_as_float(__builtin_amdgcn_update_dpp(0, __float_as_int(x), 0x122, 0xf, 0xf, true));
  x += __int_as_float(__builtin_amdgcn_update_dpp(0, __float_as_int(x), 0x121, 0xf, 0xf, true));
  return x;
}
__device__ __forceinline__ float leaky(float g){
  float a = __uint_as_float(__float_as_uint(g) & 0x7fffffffu);   // |g|
  return fmaf(0.4f, a, 0.6f*g);                                  // max(g,0)+0.2min(g,0)
}

// ---------------- dtype detector: f32 inputs (flag=1) vs bf16 (flag=0) ----------------
__global__ __launch_bounds__(256) void k_detect(const unsigned short* __restrict__ xu, int* __restrict__ flag){
  __shared__ int cnt[256];
  int tid = threadIdx.x;
  unsigned short lo = xu[2*tid];
  bf16 h = *(const bf16*)&lo;
  float v = fabsf(__bfloat162float(h));
  cnt[tid] = (v > 1e4f || (v != 0.f && v < 1e-4f)) ? 1 : 0;
  __syncthreads();
  for (int s=128; s>0; s>>=1){ if (tid<s) cnt[tid]+=cnt[tid+s]; __syncthreads(); }
  if (tid==0) *flag = (cnt[0] > 64) ? 1 : 0;
}

// ---------------- CSR build: histogram -> scan -> scatter(+ea reorder) ----------------
__global__ __launch_bounds__(256) void k_hist(const int* __restrict__ ei, int* __restrict__ cnt, int b0){
  int z = blockIdx.z, b = b0 + z;
  int e = blockIdx.x*256 + threadIdx.x;
  int d = ei[((size_t)b*2+1)*E + e];
  atomicAdd(&cnt[z*N + d], 1);
}

__global__ __launch_bounds__(256) void k_scan(const int* __restrict__ cnt, int* __restrict__ rowptr,
                                              int* __restrict__ cursor){
  int z = blockIdx.z, tid = threadIdx.x;
  const int* c = cnt + (size_t)z*N;
  int* rp = rowptr + (size_t)z*(N+1);
  int* cu = cursor + (size_t)z*N;
  const int CHK = (N + 255)/256;
  int lo = tid*CHK; int hi = lo + CHK; if (hi > N) hi = N; if (lo > N) lo = N;
  int s = 0;
  for (int i=lo;i<hi;i++) s += c[i];
  __shared__ int buf[256];
  buf[tid] = s; __syncthreads();
  for (int off=1; off<256; off<<=1){
    int t = (tid>=off) ? buf[tid-off] : 0;
    __syncthreads();
    buf[tid] += t;
    __syncthreads();
  }
  int run = buf[tid] - s;         // exclusive prefix
  for (int i=lo;i<hi;i++){ int v=c[i]; rp[i]=run; cu[i]=run; run += v; }
  if (tid==255) rp[N] = run;
}

// scatter: write src index + copy edge attrs into CSR order (f32, numerically identical).
template<typename T>
__device__ __forceinline__ void scatter_body(const int* ei, int* cursor, int* csr,
                                             const T* ea, float* eacsr, int b0){
  int z = blockIdx.z, b = b0 + z;
  int e = blockIdx.x*256 + threadIdx.x;
  int s = ei[((size_t)b*2+0)*E + e];
  int d = ei[((size_t)b*2+1)*E + e];
  int pos = atomicAdd(&cursor[z*N + d], 1);
  csr[(size_t)z*E + pos] = s;
  float4* dst = (float4*)(eacsr + ((size_t)z*E + pos)*ED);
  const T* sp = ea + ((size_t)b*E + e)*ED;
  #pragma unroll
  for (int g=0; g<4; g++){
    float4 t;
    t.x = ldv(sp, g*4+0); t.y = ldv(sp, g*4+1); t.z = ldv(sp, g*4+2); t.w = ldv(sp, g*4+3);
    dst[g] = t;
  }
}
__global__ __launch_bounds__(256) void k_scatter(const int* ei, int* cursor, int* csr,
    const void* ea, float* eacsr, const int* flag, int b0){
  if (*flag) scatter_body(ei, cursor, csr, (const float*)ea, eacsr, b0);
  else       scatter_body(ei, cursor, csr, (const bf16*) ea, eacsr, b0);
}

// ---------------- conv1 node transform: 32-node tile, writes packed bf16 directly ----------------
template<typename T>
__device__ __forceinline__ void node1_body(const T* x, const T* Wl, const T* Wr,
                                           unsigned* xl1p, unsigned* xr1p, int b0,
                                           float (*xs)[F+4]){
  int z = blockIdx.z, b = b0 + z;
  int node0 = blockIdx.x*NT;
  for (int i=threadIdx.x; i<NT*F; i+=256){
    int n = i>>6, k = i&63;
    xs[n][k] = ldv(x, ((size_t)b*N + node0 + n)*F + k);
  }
  __syncthreads();
  int mat = threadIdx.x >> 7, c = threadIdx.x & 127;
  const T* W = mat ? Wr : Wl;
  float acc[NT];
  #pragma unroll
  for (int n=0;n<NT;n++) acc[n]=0.f;
  for (int k=0;k<F;k+=4){
    float w0 = ldv(W, (size_t)(k+0)*HC + c);
    float w1 = ldv(W, (size_t)(k+1)*HC + c);
    float w2 = ldv(W, (size_t)(k+2)*HC + c);
    float w3 = ldv(W, (size_t)(k+3)*HC + c);
    #pragma unroll
    for (int n=0;n<NT;n++){
      float4 xv = *(const float4*)&xs[n][k];
      acc[n] += xv.x*w0 + xv.y*w1 + xv.z*w2 + xv.w*w3;
    }
  }
  unsigned short* outp = (unsigned short*)(mat ? xr1p : xl1p);
  int half = c>>6, cc = c&63;
  #pragma unroll
  for (int n=0;n<NT;n++){
    float v = clampf(acc[n], -1e4f, 1e4f);
    outp[(((size_t)z*N + node0 + n)*64 + cc)*2 + half] = tobf(v);
  }
}
__global__ __launch_bounds__(256) void k_node1(const void* x, const void* Wl, const void* Wr,
    unsigned* xl1p, unsigned* xr1p, const int* flag, int b0){
  __shared__ float xs[NT][F+4];
  if (*flag) node1_body((const float*)x,(const float*)Wl,(const float*)Wr,xl1p,xr1p,b0,xs);
  else       node1_body((const bf16*) x,(const bf16*) Wl,(const bf16*) Wr,xl1p,xr1p,b0,xs);
}

// ---------------- conv1 fused gather: wave-per-node, ea register double-buffer ----------------
// Per edge: ee-dot as plain scalar FMA (pk_fma has no throughput benefit on gfx950 —
// round-4 lesson). eA/eB alternate edge-attr rows so the load→use chain of edge i+1
// overlaps edge i's ~130-cycle compute. xl gather stays 2-deep prefetched.
template<typename T>
__device__ __forceinline__ void gather1_body(const int* __restrict__ rowptr, const int* __restrict__ csr,
    const float* __restrict__ eacsr, const T* __restrict__ We, const T* __restrict__ att, const T* __restrict__ b1,
    const unsigned* __restrict__ xl1p, const unsigned* __restrict__ xr1p, float* __restrict__ hx, int b0){
  int z = blockIdx.z;
  int lane = threadIdx.x & 63;
  int node = rfl(blockIdx.x*4 + (threadIdx.x >> 6));
  int rs = rfl(rowptr[(size_t)z*(N+1) + node]);
  int re = rfl(rowptr[(size_t)z*(N+1) + node + 1]);
  f32x2 w[ED];
  #pragma unroll
  for (int j=0;j<ED;j++) w[j] = mk2(ldv(We,(size_t)j*HC+lane), ldv(We,(size_t)j*HC+lane+64));
  float attL = ldv(att,(size_t)lane)*L2E, attH = ldv(att,(size_t)lane+64)*L2E;
  unsigned xru = xr1p[((size_t)z*N + node)*64 + lane];
  f32x2 xr2 = mk2(unpl(xru), unph(xru));
  f32x2 acc = mk2(0.f,0.f), den = mk2(0.f,0.f);
  const unsigned* __restrict__ xlp = xl1p + (size_t)z*N*64;
  const int* __restrict__ csrz = csr + (size_t)z*E + rs;
  const f32x2* __restrict__ eaz = (const f32x2*)(eacsr + ((size_t)z*E + rs)*ED);
  int deg = re - rs;
  if (deg > 0){
    auto EDGE = [&](const f32x2* er, unsigned xw){
      f32x2 xl = mk2(unpl(xw), unph(xw));
      f32x2 g0 = xl + xr2, g1 = mk2(0.f,0.f);
      #pragma unroll
      for (int jp=0;jp<8;jp++){ g0 += w[2*jp]*er[jp].x; g1 += w[2*jp+1]*er[jp].y; }
      f32x2 g = g0 + g1;
      float vL = rsum16(leaky(g.x)*attL);
      float vH = rsum16(leaky(g.y)*attH);
      f32x2 ex = mk2(exp2f(clampf(vL,-86.f,86.f)), exp2f(clampf(vH,-86.f,86.f)));
      den += ex;
      acc += ex*xl;
    };
    int s0 = rfl(csrz[0]);
    int s1 = (deg>1) ? rfl(csrz[1]) : s0;
    unsigned xa = xlp[(size_t)(unsigned)s0*64 + lane];
    unsigned xb = xlp[(size_t)(unsigned)s1*64 + lane];
    f32x2 eA[8], eB[8];
    #pragma unroll
    for (int p=0;p<8;p++) eA[p] = eaz[p];
    int i = 0;
    for (; i+1 < deg; i += 2){
      #pragma unroll
      for (int p=0;p<8;p++) eB[p] = eaz[(size_t)(i+1)*8 + p];
      unsigned x0 = xa, x1 = xb;
      if (i+2 < deg){ int sn = rfl(csrz[i+2]); xa = xlp[(size_t)(unsigned)sn*64 + lane]; }
      if (i+3 < deg){ int sn = rfl(csrz[i+3]); xb = xlp[(size_t)(unsigned)sn*64 + lane]; }
      EDGE(eA, x0);
      if (i+2 < deg){
        #pragma unroll
        for (int p=0;p<8;p++) eA[p] = eaz[(size_t)(i+2)*8 + p];
      }
      EDGE(eB, x1);
    }
    if (i < deg) EDGE(eA, xa);
  }
  float hL = acc.x/(den.x + 1e-16f) + ldv(b1,(size_t)lane);
  float hH = acc.y/(den.y + 1e-16f) + ldv(b1,(size_t)lane+64);
  hL = hL>0.f ? hL : expm1f(hL);
  hH = hH>0.f ? hH : expm1f(hH);
  hx[((size_t)z*N + node)*HC + lane]      = hL;
  hx[((size_t)z*N + node)*HC + lane + 64] = hH;
}
__global__ __launch_bounds__(256) void k_gather1(const int* __restrict__ rowptr, const int* __restrict__ csr,
    const float* __restrict__ eacsr,
    const void* We, const void* att, const void* b1,
    const unsigned* __restrict__ xl1p, const unsigned* __restrict__ xr1p, float* __restrict__ hx,
    const int* __restrict__ flag, int b0){
  if (*flag) gather1_body(rowptr,csr,eacsr,(const float*)We,(const float*)att,(const float*)b1,xl1p,xr1p,hx,b0);
  else       gather1_body(rowptr,csr,eacsr,(const bf16*) We,(const bf16*) att,(const bf16*) b1,xl1p,xr1p,hx,b0);
}

// ---------------- conv2/conv3 node transforms: 32-node tile, writes packed bf16 directly ----------------
template<typename T>
__device__ __forceinline__ void node2_body(const float* hx, const unsigned* xl1p,
    const T* W2l, const T* W2r, const T* W3l, const T* W3r,
    unsigned* xl23p, unsigned* xr23p, int b0,
    float (*hv)[HC+4], float (*sv)[HC+4]){
  int z = blockIdx.z;
  int node0 = blockIdx.x*NT;
  for (int i=threadIdx.x; i<NT*HC; i+=256){
    int n = i>>7, k = i&127;
    float h = hx[((size_t)z*N + node0 + n)*HC + k];
    unsigned wxl = xl1p[((size_t)z*N + node0 + n)*64 + (k&63)];
    float xv = (k<64) ? unpl(wxl) : unph(wxl);
    hv[n][k] = h;
    sv[n][k] = h + xv;                // hs = hx + skip(=xl1)
  }
  __syncthreads();
  int o = threadIdx.x & 63;
  int mat = o >> 4, c = o & 15;
  int g = threadIdx.x >> 6;
  const T* W = (mat==0)? W2l : (mat==1)? W2r : (mat==2)? W3l : W3r;
  float (*src)[HC+4] = (mat<2)? hv : sv;
  float acc[8];
  #pragma unroll
  for (int j=0;j<8;j++) acc[j]=0.f;
  for (int k=0;k<HC;k+=4){
    float w0 = ldv(W, (size_t)(k+0)*CH + c);
    float w1 = ldv(W, (size_t)(k+1)*CH + c);
    float w2 = ldv(W, (size_t)(k+2)*CH + c);
    float w3 = ldv(W, (size_t)(k+3)*CH + c);
    #pragma unroll
    for (int j=0;j<8;j++){
      float4 xv = *(const float4*)&src[g*8+j][k];
      acc[j] += xv.x*w0 + xv.y*w1 + xv.z*w2 + xv.w*w3;
    }
  }
  unsigned short* arr = (unsigned short*)((mat&1) ? xr23p : xl23p);
  int half = mat>>1;
  #pragma unroll
  for (int j=0;j<8;j++){
    float v = clampf(acc[j], -1e4f, 1e4f);
    arr[(((size_t)z*N + node0 + g*8 + j)*CH + c)*2 + half] = tobf(v);
  }
}
__global__ __launch_bounds__(256) void k_node2(const float* hx, const unsigned* xl1p,
    const void* W2l, const void* W2r, const void* W3l, const void* W3r,
    unsigned* xl23p, unsigned* xr23p, const int* flag, int b0){
  __shared__ float hv[NT][HC+4];
  __shared__ float sv[NT][HC+4];
  if (*flag) node2_body(hx,xl1p,(const float*)W2l,(const float*)W2r,(const float*)W3l,(const float*)W3r,xl23p,xr23p,b0,hv,sv);
  else       node2_body(hx,xl1p,(const bf16*) W2l,(const bf16*) W2r,(const bf16*) W3l,(const bf16*) W3r,xl23p,xr23p,b0,hv,sv);
}

// ---------------- conv2+conv3 fused gather + linear + LayerNorm + store ----------------
// Slot-based (round-2 measured-best): 16 slots of 16 lanes; (conv2,conv3) packed per lane.
template<typename T>
__device__ __forceinline__ void gather23_body(const int* __restrict__ rowptr, const int* __restrict__ csr,
    const float* __restrict__ eacsr,
    const T* We2, const T* We3, const T* att2, const T* att3,
    const T* b2, const T* b3, const T* linW, const T* linb, const T* lng, const T* lnb,
    const unsigned* __restrict__ xl23p, const unsigned* __restrict__ xr23p,
    T* out, int b0, int (*ssrc)[TB2], float (*eas)[TB2][16]){
  int z = blockIdx.z;
  int slot = threadIdx.x >> 4;            // 16 slots of 16 lanes
  int node = blockIdx.x*16 + slot;
  int c = threadIdx.x & 15;
  int rs = rowptr[(size_t)z*(N+1) + node];
  int re = rowptr[(size_t)z*(N+1) + node + 1];
  unsigned xru = xr23p[((size_t)z*N + node)*CH + c];
  f32x2 xr2 = mk2(unpl(xru), unph(xru));  // (conv2, skip-conv)
  f32x2 w[ED];
  #pragma unroll
  for (int j=0;j<ED;j++) w[j] = mk2(ldv(We2,(size_t)j*CH+c), ldv(We3,(size_t)j*CH+c));
  f32x2 attv = mk2(ldv(att2,(size_t)c)*L2E, ldv(att3,(size_t)c)*L2E);
  f32x2 acc = mk2(0.f,0.f), den = mk2(0.f,0.f);
  const unsigned* __restrict__ xlp = xl23p + (size_t)z*N*CH;
  const int* __restrict__ csrz = csr + (size_t)z*E;

  auto edge = [&](int i, unsigned xw){
    f32x2 xl = mk2(unpl(xw), unph(xw));
    float ev[16];
    const float4* er = (const float4*)eas[slot][i];
    *(float4*)&ev[0]  = er[0];
    *(float4*)&ev[4]  = er[1];
    *(float4*)&ev[8]  = er[2];
    *(float4*)&ev[12] = er[3];
    f32x2 g0 = xl + xr2, g1 = mk2(0.f,0.f);
    #pragma unroll
    for (int j=0;j<ED;j+=2){ g0 += w[j]*ev[j]; g1 += w[j+1]*ev[j+1]; }
    f32x2 gg = g0 + g1;
    f32x2 lr = mk2(leaky(gg.x), leaky(gg.y));
    f32x2 v = lr*attv;
    float v2 = rsum16(v.x);
    float v3 = rsum16(v.y);
    f32x2 ex = mk2(exp2f(clampf(v2,-86.f,86.f)), exp2f(clampf(v3,-86.f,86.f)));
    den += ex;
    acc += ex*xl;
  };

  for (int base = rs; base < re; base += TB2){
    int m = re - base; if (m > TB2) m = TB2;
    if (c < m) ssrc[slot][c] = csrz[base + c];
    const float4* ep = (const float4*)(eacsr + ((size_t)z*E + base)*ED);
    for (int i4=c; i4<m*4; i4+=16)
      *(float4*)&eas[slot][i4>>2][(i4&3)*4] = ep[i4];
    unsigned pa = xlp[(unsigned)(ssrc[slot][0]*CH + c)];
    unsigned pb = (m>1) ? xlp[(unsigned)(ssrc[slot][1]*CH + c)] : pa;
    int i = 0;
    for (; i+1 < m; i += 2){
      unsigned x0 = pa, x1 = pb;
      int i2 = (i+2 < m) ? i+2 : m-1;
      int i3 = (i+3 < m) ? i+3 : m-1;
      int s2 = ssrc[slot][i2], s3 = ssrc[slot][i3];
      pa = xlp[(unsigned)(s2*CH + c)];
      pb = xlp[(unsigned)(s3*CH + c)];
      edge(i, x0);
      edge(i+1, x1);
    }
    if (i < m) edge(i, pa);
  }
  float x1 = acc.x/(den.x + 1e-16f) + ldv(b2,(size_t)c);   // conv2 output
  float x3 = acc.y/(den.y + 1e-16f) + ldv(b3,(size_t)c);   // skip-conv output
  float x2 = 0.f;
  #pragma unroll
  for (int j=0;j<16;j++) x2 += __shfl(x3, j, 16) * ldv(linW, (size_t)c*16 + j);
  x2 += ldv(linb,(size_t)c);
  float y = clampf(x1, -1e6f, 1e6f) + clampf(x2, -1e6f, 1e6f);
  float mu = rsum16(y)*(1.f/16.f);
  float dv = y - mu;
  float var = rsum16(dv*dv)*(1.f/16.f);
  float o = dv*rsqrtf(var + 1e-5f)*ldv(lng,(size_t)c) + ldv(lnb,(size_t)c);
  stv(out, ((size_t)(b0+z)*N + node)*16 + c, o);
}
__global__ __launch_bounds__(256) void k_gather23(const int* __restrict__ rowptr, const int* __restrict__ csr,
    const float* __restrict__ eacsr,
    const void* We2, const void* We3, const void* att2, const void* att3,
    const void* b2, const void* b3, const void* linW, const void* linb, const void* lng, const void* lnb,
    const unsigned* __restrict__ xl23p, const unsigned* __restrict__ xr23p,
    void* out, const int* __restrict__ flag, int b0){
  __shared__ int ssrc[16][TB2];
  __shared__ float eas[16][TB2][16];
  if (*flag) gather23_body(rowptr,csr,eacsr,(const float*)We2,(const float*)We3,(const float*)att2,(const float*)att3,
                           (const float*)b2,(const float*)b3,(const float*)linW,(const float*)linb,(const float*)lng,(const float*)lnb,
                           xl23p,xr23p,(float*)out,b0,ssrc,eas);
  else       gather23_body(rowptr,csr,eacsr,(const bf16*) We2,(const bf16*) We3,(const bf16*) att2,(const bf16*) att3,
                           (const bf16*) b2,(const bf16*) b3,(const bf16*) linW,(const bf16*) linb,(const bf16*) lng,(const bf16*) lnb,
                           xl23p,xr23p,(bf16*) out,b0,ssrc,eas);
}

// ---------------- workspace layout ----------------
struct WSP {
  int* flag;
  int *cnt, *cursor, *rowptr; int* csr;
  float *eacsr, *hx;
  unsigned *xl1p,*xr1p,*xl23p,*xr23p;
  size_t total;
};
static WSP mkws(char* base, int nb){
  WSP w; size_t off = 0;
  auto A = [&](size_t bytes)->char*{ char* p = base ? base + off : (char*)0; off = (off + bytes + 255) & ~(size_t)255; return p; };
  w.flag   = (int*)     A(256);
  w.cnt    = (int*)     A((size_t)nb*N*4);
  w.cursor = (int*)     A((size_t)nb*N*4);
  w.rowptr = (int*)     A((size_t)nb*(N+1)*4);
  w.csr    = (int*)     A((size_t)nb*E*4);
  w.eacsr  = (float*)   A((size_t)nb*E*ED*4);
  w.hx     = (float*)   A((size_t)nb*N*HC*4);
  w.xl1p   = (unsigned*)A((size_t)nb*N*64*4);
  w.xr1p   = (unsigned*)A((size_t)nb*N*64*4);
  w.xl23p  = (unsigned*)A((size_t)nb*N*CH*4);
  w.xr23p  = (unsigned*)A((size_t)nb*N*CH*4);
  w.total = off;
  return w;
}

extern "C" void kernel_launch(void* const* d_in, const int* in_sizes, int n_in,
                              void* d_out, int out_size, void* d_ws, size_t ws_size,
                              hipStream_t stream){
  const void* x    = d_in[0];
  const void* ea   = d_in[1];
  const int*  ei   = (const int*)d_in[2];
  const void* c1Wl = d_in[3], *c1Wr = d_in[4], *c1We = d_in[5];
  const void* c1att= d_in[6], *c1b  = d_in[7];
  const void* c2Wl = d_in[8], *c2Wr = d_in[9], *c2We = d_in[10];
  const void* c2att= d_in[11],*c2b  = d_in[12];
  const void* sWl  = d_in[13],*sWr  = d_in[14],*sWe  = d_in[15];
  const void* satt = d_in[16],*sb   = d_in[17];
  const void* linW = d_in[18],*linb = d_in[19];
  const void* lng  = d_in[20],*lnb  = d_in[21];

  auto run = [&](int b0, int nb){
    WSP w = mkws((char*)d_ws, nb);
    hipMemsetAsync(w.cnt, 0, (size_t)nb*N*4, stream);
    k_hist   <<<dim3(E/256,1,nb),   256,0,stream>>>(ei, w.cnt, b0);
    k_scan   <<<dim3(1,1,nb),       256,0,stream>>>(w.cnt, w.rowptr, w.cursor);
    k_scatter<<<dim3(E/256,1,nb),   256,0,stream>>>(ei, w.cursor, w.csr, ea, w.eacsr, w.flag, b0);
    // conv1
    k_node1  <<<dim3(N/NT,1,nb),    256,0,stream>>>(x, c1Wl, c1Wr, w.xl1p, w.xr1p, w.flag, b0);
    k_gather1<<<dim3(N/4,1,nb),     256,0,stream>>>(w.rowptr, w.csr, w.eacsr, c1We, c1att, c1b,
                                                    w.xl1p, w.xr1p, w.hx, w.flag, b0);
    // conv2 + skip-conv
    k_node2  <<<dim3(N/NT,1,nb),    256,0,stream>>>(w.hx, w.xl1p, c2Wl, c2Wr, sWl, sWr,
                                                    w.xl23p, w.xr23p, w.flag, b0);
    k_gather23<<<dim3(N/16,1,nb),   256,0,stream>>>(w.rowptr, w.csr, w.eacsr, c2We, sWe, c2att, satt,
                                                    c2b, sb, linW, linb, lng, lnb,
                                                    w.xl23p, w.xr23p, d_out, w.flag, b0);
  };

  {
    WSP w0 = mkws((char*)d_ws, 1);
    k_detect<<<1,256,0,stream>>>((const unsigned short*)x, w0.flag);
  }

  WSP probe = mkws((char*)0, NB_B);
  if (ws_size >= probe.total){
    run(0, NB_B);                          // single batched pass
  } else {
    for (int g=0; g<NB_B; ++g) run(g, 1);  // per-graph fallback
  }
}

// Round 6
// 1027.881 us; speedup vs baseline: 1.2358x; 1.1101x over previous
//
#include <hip/hip_runtime.h>
#include <hip/hip_bf16.h>

typedef __hip_bfloat16 bf16;
typedef float f32x2 __attribute__((ext_vector_type(2)));
typedef _Float16 h2 __attribute__((ext_vector_type(2)));

#define NB_B 4
#define N 20000
#define E 640000
#define F 64
#define HC 128   // conv1 heads*ch
#define ED 16
#define CH 16
#define NT 32    // nodes per tile in node-transform kernels
#define TB2 16   // edge tile per slot, gather23

__device__ __forceinline__ float clampf(float v, float lo, float hi){ return fminf(fmaxf(v, lo), hi); }
__device__ __forceinline__ float ldv(const float* p, size_t i){ return p[i]; }
__device__ __forceinline__ float ldv(const bf16*  p, size_t i){ return __bfloat162float(p[i]); }
__device__ __forceinline__ void  stv(float* p, size_t i, float v){ p[i] = v; }
__device__ __forceinline__ void  stv(bf16*  p, size_t i, float v){ p[i] = __float2bfloat16(v); }
__device__ __forceinline__ unsigned short tobf(float v){ bf16 b = __float2bfloat16(v); return *(unsigned short*)&b; }
__device__ __forceinline__ float unpl(unsigned u){ return __uint_as_float(u << 16); }
__device__ __forceinline__ float unph(unsigned u){ return __uint_as_float(u & 0xffff0000u); }
__device__ __forceinline__ f32x2 mk2(float a, float b){ f32x2 r; r.x = a; r.y = b; return r; }
__device__ __forceinline__ int rfl(int v){ return __builtin_amdgcn_readfirstlane(v); }

// f16 pair pack + single-slot dual-MAC dot (v_dot2_f32_f16, f32 accumulate)
__device__ __forceinline__ unsigned packh2(float a, float b){
  _Float16 x = (_Float16)a, y = (_Float16)b;
  unsigned short ux = *(unsigned short*)&x, uy = *(unsigned short*)&y;
  return (unsigned)ux | ((unsigned)uy << 16);
}
__device__ __forceinline__ float dot2(unsigned a, unsigned b, float c){
  h2 ha = *(h2*)&a, hb = *(h2*)&b;
  return __builtin_amdgcn_fdot2(ha, hb, c, false);
}

#define L2E 1.44269504f

// 16-lane (DPP row) all-reduce sum: pure VALU (row_ror butterfly 8,4,2,1).
__device__ __forceinline__ float rsum16(float x){
  x += __int_as_float(__builtin_amdgcn_update_dpp(0, __float_as_int(x), 0x128, 0xf, 0xf, true));
  x += __int_as_float(__builtin_amdgcn_update_dpp(0, __float_as_int(x), 0x124, 0xf, 0xf, true));
  x += __int_as_float(__builtin_amdgcn_update_dpp(0, __float_as_int(x), 0x122, 0xf, 0xf, true));
  x += __int_as_float(__builtin_amdgcn_update_dpp(0, __float_as_int(x), 0x121, 0xf, 0xf, true));
  return x;
}
__device__ __forceinline__ float leaky(float g){
  float a = __uint_as_float(__float_as_uint(g) & 0x7fffffffu);   // |g|
  return fmaf(0.4f, a, 0.6f*g);                                  // max(g,0)+0.2min(g,0)
}

// ---------------- dtype detector: f32 inputs (flag=1) vs bf16 (flag=0) ----------------
__global__ __launch_bounds__(256) void k_detect(const unsigned short* __restrict__ xu, int* __restrict__ flag){
  __shared__ int cnt[256];
  int tid = threadIdx.x;
  unsigned short lo = xu[2*tid];
  bf16 h = *(const bf16*)&lo;
  float v = fabsf(__bfloat162float(h));
  cnt[tid] = (v > 1e4f || (v != 0.f && v < 1e-4f)) ? 1 : 0;
  __syncthreads();
  for (int s=128; s>0; s>>=1){ if (tid<s) cnt[tid]+=cnt[tid+s]; __syncthreads(); }
  if (tid==0) *flag = (cnt[0] > 64) ? 1 : 0;
}

// ---------------- CSR build: histogram -> scan -> scatter(+ea reorder to f16 pairs) ----------------
__global__ __launch_bounds__(256) void k_hist(const int* __restrict__ ei, int* __restrict__ cnt, int b0){
  int z = blockIdx.z, b = b0 + z;
  int e = blockIdx.x*256 + threadIdx.x;
  int d = ei[((size_t)b*2+1)*E + e];
  atomicAdd(&cnt[z*N + d], 1);
}

__global__ __launch_bounds__(256) void k_scan(const int* __restrict__ cnt, int* __restrict__ rowptr,
                                              int* __restrict__ cursor){
  int z = blockIdx.z, tid = threadIdx.x;
  const int* c = cnt + (size_t)z*N;
  int* rp = rowptr + (size_t)z*(N+1);
  int* cu = cursor + (size_t)z*N;
  const int CHK = (N + 255)/256;
  int lo = tid*CHK; int hi = lo + CHK; if (hi > N) hi = N; if (lo > N) lo = N;
  int s = 0;
  for (int i=lo;i<hi;i++) s += c[i];
  __shared__ int buf[256];
  buf[tid] = s; __syncthreads();
  for (int off=1; off<256; off<<=1){
    int t = (tid>=off) ? buf[tid-off] : 0;
    __syncthreads();
    buf[tid] += t;
    __syncthreads();
  }
  int run = buf[tid] - s;         // exclusive prefix
  for (int i=lo;i<hi;i++){ int v=c[i]; rp[i]=run; cu[i]=run; run += v; }
  if (tid==255) rp[N] = run;
}

// scatter: src index + edge attrs into CSR order as f16 j-pairs (8 words = 32B/edge).
template<typename T>
__device__ __forceinline__ void scatter_body(const int* ei, int* cursor, int* csr,
                                             const T* ea, unsigned* ea8, int b0){
  int z = blockIdx.z, b = b0 + z;
  int e = blockIdx.x*256 + threadIdx.x;
  int s = ei[((size_t)b*2+0)*E + e];
  int d = ei[((size_t)b*2+1)*E + e];
  int pos = atomicAdd(&cursor[z*N + d], 1);
  csr[(size_t)z*E + pos] = s;
  const T* sp = ea + ((size_t)b*E + e)*ED;
  uint4 q0, q1;
  q0.x = packh2(ldv(sp,0),  ldv(sp,1));
  q0.y = packh2(ldv(sp,2),  ldv(sp,3));
  q0.z = packh2(ldv(sp,4),  ldv(sp,5));
  q0.w = packh2(ldv(sp,6),  ldv(sp,7));
  q1.x = packh2(ldv(sp,8),  ldv(sp,9));
  q1.y = packh2(ldv(sp,10), ldv(sp,11));
  q1.z = packh2(ldv(sp,12), ldv(sp,13));
  q1.w = packh2(ldv(sp,14), ldv(sp,15));
  uint4* dst = (uint4*)(ea8 + ((size_t)z*E + pos)*8);
  dst[0] = q0; dst[1] = q1;
}
__global__ __launch_bounds__(256) void k_scatter(const int* ei, int* cursor, int* csr,
    const void* ea, unsigned* ea8, const int* flag, int b0){
  if (*flag) scatter_body(ei, cursor, csr, (const float*)ea, ea8, b0);
  else       scatter_body(ei, cursor, csr, (const bf16*) ea, ea8, b0);
}

// ---------------- conv1 node transform: 32-node tile, writes packed bf16 directly ----------------
template<typename T>
__device__ __forceinline__ void node1_body(const T* x, const T* Wl, const T* Wr,
                                           unsigned* xl1p, unsigned* xr1p, int b0,
                                           float (*xs)[F+4]){
  int z = blockIdx.z, b = b0 + z;
  int node0 = blockIdx.x*NT;
  for (int i=threadIdx.x; i<NT*F; i+=256){
    int n = i>>6, k = i&63;
    xs[n][k] = ldv(x, ((size_t)b*N + node0 + n)*F + k);
  }
  __syncthreads();
  int mat = threadIdx.x >> 7, c = threadIdx.x & 127;
  const T* W = mat ? Wr : Wl;
  float acc[NT];
  #pragma unroll
  for (int n=0;n<NT;n++) acc[n]=0.f;
  for (int k=0;k<F;k+=4){
    float w0 = ldv(W, (size_t)(k+0)*HC + c);
    float w1 = ldv(W, (size_t)(k+1)*HC + c);
    float w2 = ldv(W, (size_t)(k+2)*HC + c);
    float w3 = ldv(W, (size_t)(k+3)*HC + c);
    #pragma unroll
    for (int n=0;n<NT;n++){
      float4 xv = *(const float4*)&xs[n][k];
      acc[n] += xv.x*w0 + xv.y*w1 + xv.z*w2 + xv.w*w3;
    }
  }
  unsigned short* outp = (unsigned short*)(mat ? xr1p : xl1p);
  int half = c>>6, cc = c&63;
  #pragma unroll
  for (int n=0;n<NT;n++){
    float v = clampf(acc[n], -1e4f, 1e4f);
    outp[(((size_t)z*N + node0 + n)*64 + cc)*2 + half] = tobf(v);
  }
}
__global__ __launch_bounds__(256) void k_node1(const void* x, const void* Wl, const void* Wr,
    unsigned* xl1p, unsigned* xr1p, const int* flag, int b0){
  __shared__ float xs[NT][F+4];
  if (*flag) node1_body((const float*)x,(const float*)Wl,(const float*)Wr,xl1p,xr1p,b0,xs);
  else       node1_body((const bf16*) x,(const bf16*) Wl,(const bf16*) Wr,xl1p,xr1p,b0,xs);
}

// ---------------- conv1 fused gather: wave-per-node, f16 dot2 ee-dot ----------------
// Per edge: 16 v_dot2_f32_f16 (both channel halves) + ~30 epilogue VALU. Weights are
// 16 packed f16-pair words (cvt+pack chain makes remat unprofitable). ea row = 2 dwordx4.
template<typename T>
__device__ __forceinline__ void gather1_body(const int* __restrict__ rowptr, const int* __restrict__ csr,
    const unsigned* __restrict__ ea8, const T* __restrict__ We, const T* __restrict__ att, const T* __restrict__ b1,
    const unsigned* __restrict__ xl1p, const unsigned* __restrict__ xr1p, float* __restrict__ hx, int b0){
  int z = blockIdx.z;
  int lane = threadIdx.x & 63;
  int node = rfl(blockIdx.x*4 + (threadIdx.x >> 6));
  int rs = rfl(rowptr[(size_t)z*(N+1) + node]);
  int re = rfl(rowptr[(size_t)z*(N+1) + node + 1]);
  unsigned wA[8], wB[8];                 // f16-pair weights: ch lane / ch lane+64
  #pragma unroll
  for (int jp=0;jp<8;jp++){
    wA[jp] = packh2(ldv(We,(size_t)(2*jp)*HC+lane),    ldv(We,(size_t)(2*jp+1)*HC+lane));
    wB[jp] = packh2(ldv(We,(size_t)(2*jp)*HC+lane+64), ldv(We,(size_t)(2*jp+1)*HC+lane+64));
  }
  float attL = ldv(att,(size_t)lane)*L2E, attH = ldv(att,(size_t)lane+64)*L2E;
  unsigned xru = xr1p[((size_t)z*N + node)*64 + lane];
  float xrL = unpl(xru), xrH = unph(xru);
  float accL=0.f, accH=0.f, denL=0.f, denH=0.f;
  const unsigned* __restrict__ xlp = xl1p + (size_t)z*N*64;
  const int* __restrict__ csrz = csr + (size_t)z*E + rs;
  const uint4* __restrict__ ep = (const uint4*)(ea8 + ((size_t)z*E + rs)*8);
  int deg = re - rs;
  if (deg > 0){
    int s0 = rfl(csrz[0]);
    int s1 = (deg>1) ? rfl(csrz[1]) : s0;
    unsigned xa = (xlp + (size_t)(unsigned)s0*64)[lane];
    unsigned xb = (xlp + (size_t)(unsigned)s1*64)[lane];
    uint4 e0 = ep[0], e1 = ep[1];
    for (int i=0;i<deg;i++){
      unsigned xw = xa; xa = xb;
      uint4 c0 = e0, c1 = e1;
      if (i+1 < deg){ e0 = ep[2*(i+1)]; e1 = ep[2*(i+1)+1]; }
      if (i+2 < deg){
        int sn = rfl(csrz[i+2]);
        xb = (xlp + (size_t)(unsigned)sn*64)[lane];
      }
      float xlL = unpl(xw), xlH = unph(xw);
      float gL = xlL + xrL, gH = xlH + xrH;
      gL = dot2(c0.x, wA[0], gL);  gH = dot2(c0.x, wB[0], gH);
      gL = dot2(c0.y, wA[1], gL);  gH = dot2(c0.y, wB[1], gH);
      gL = dot2(c0.z, wA[2], gL);  gH = dot2(c0.z, wB[2], gH);
      gL = dot2(c0.w, wA[3], gL);  gH = dot2(c0.w, wB[3], gH);
      gL = dot2(c1.x, wA[4], gL);  gH = dot2(c1.x, wB[4], gH);
      gL = dot2(c1.y, wA[5], gL);  gH = dot2(c1.y, wB[5], gH);
      gL = dot2(c1.z, wA[6], gL);  gH = dot2(c1.z, wB[6], gH);
      gL = dot2(c1.w, wA[7], gL);  gH = dot2(c1.w, wB[7], gH);
      float vL = rsum16(leaky(gL)*attL);
      float vH = rsum16(leaky(gH)*attH);
      float exL = exp2f(clampf(vL,-86.f,86.f));
      float exH = exp2f(clampf(vH,-86.f,86.f));
      denL += exL; denH += exH;
      accL = fmaf(exL, xlL, accL);
      accH = fmaf(exH, xlH, accH);
    }
  }
  float hL = accL/(denL + 1e-16f) + ldv(b1,(size_t)lane);
  float hH = accH/(denH + 1e-16f) + ldv(b1,(size_t)lane+64);
  hL = hL>0.f ? hL : expm1f(hL);
  hH = hH>0.f ? hH : expm1f(hH);
  hx[((size_t)z*N + node)*HC + lane]      = hL;
  hx[((size_t)z*N + node)*HC + lane + 64] = hH;
}
__global__ __launch_bounds__(256) void k_gather1(const int* __restrict__ rowptr, const int* __restrict__ csr,
    const unsigned* __restrict__ ea8,
    const void* We, const void* att, const void* b1,
    const unsigned* __restrict__ xl1p, const unsigned* __restrict__ xr1p, float* __restrict__ hx,
    const int* __restrict__ flag, int b0){
  if (*flag) gather1_body(rowptr,csr,ea8,(const float*)We,(const float*)att,(const float*)b1,xl1p,xr1p,hx,b0);
  else       gather1_body(rowptr,csr,ea8,(const bf16*) We,(const bf16*) att,(const bf16*) b1,xl1p,xr1p,hx,b0);
}

// ---------------- conv2/conv3 node transforms: 32-node tile, writes packed bf16 directly ----------------
template<typename T>
__device__ __forceinline__ void node2_body(const float* hx, const unsigned* xl1p,
    const T* W2l, const T* W2r, const T* W3l, const T* W3r,
    unsigned* xl23p, unsigned* xr23p, int b0,
    float (*hv)[HC+4], float (*sv)[HC+4]){
  int z = blockIdx.z;
  int node0 = blockIdx.x*NT;
  for (int i=threadIdx.x; i<NT*HC; i+=256){
    int n = i>>7, k = i&127;
    float h = hx[((size_t)z*N + node0 + n)*HC + k];
    unsigned wxl = xl1p[((size_t)z*N + node0 + n)*64 + (k&63)];
    float xv = (k<64) ? unpl(wxl) : unph(wxl);
    hv[n][k] = h;
    sv[n][k] = h + xv;                // hs = hx + skip(=xl1)
  }
  __syncthreads();
  int o = threadIdx.x & 63;
  int mat = o >> 4, c = o & 15;
  int g = threadIdx.x >> 6;
  const T* W = (mat==0)? W2l : (mat==1)? W2r : (mat==2)? W3l : W3r;
  float (*src)[HC+4] = (mat<2)? hv : sv;
  float acc[8];
  #pragma unroll
  for (int j=0;j<8;j++) acc[j]=0.f;
  for (int k=0;k<HC;k+=4){
    float w0 = ldv(W, (size_t)(k+0)*CH + c);
    float w1 = ldv(W, (size_t)(k+1)*CH + c);
    float w2 = ldv(W, (size_t)(k+2)*CH + c);
    float w3 = ldv(W, (size_t)(k+3)*CH + c);
    #pragma unroll
    for (int j=0;j<8;j++){
      float4 xv = *(const float4*)&src[g*8+j][k];
      acc[j] += xv.x*w0 + xv.y*w1 + xv.z*w2 + xv.w*w3;
    }
  }
  unsigned short* arr = (unsigned short*)((mat&1) ? xr23p : xl23p);
  int half = mat>>1;
  #pragma unroll
  for (int j=0;j<8;j++){
    float v = clampf(acc[j], -1e4f, 1e4f);
    arr[(((size_t)z*N + node0 + g*8 + j)*CH + c)*2 + half] = tobf(v);
  }
}
__global__ __launch_bounds__(256) void k_node2(const float* hx, const unsigned* xl1p,
    const void* W2l, const void* W2r, const void* W3l, const void* W3r,
    unsigned* xl23p, unsigned* xr23p, const int* flag, int b0){
  __shared__ float hv[NT][HC+4];
  __shared__ float sv[NT][HC+4];
  if (*flag) node2_body(hx,xl1p,(const float*)W2l,(const float*)W2r,(const float*)W3l,(const float*)W3r,xl23p,xr23p,b0,hv,sv);
  else       node2_body(hx,xl1p,(const bf16*) W2l,(const bf16*) W2r,(const bf16*) W3l,(const bf16*) W3r,xl23p,xr23p,b0,hv,sv);
}

// ---------------- conv2+conv3 fused gather + linear + LayerNorm + store ----------------
// Slot-based (measured-best structure); ee-dot via f16 dot2, LDS staging halved (8 words/edge).
template<typename T>
__device__ __forceinline__ void gather23_body(const int* __restrict__ rowptr, const int* __restrict__ csr,
    const unsigned* __restrict__ ea8,
    const T* We2, const T* We3, const T* att2, const T* att3,
    const T* b2, const T* b3, const T* linW, const T* linb, const T* lng, const T* lnb,
    const unsigned* __restrict__ xl23p, const unsigned* __restrict__ xr23p,
    T* out, int b0, int (*ssrc)[TB2], unsigned (*eas)[TB2][8]){
  int z = blockIdx.z;
  int slot = threadIdx.x >> 4;            // 16 slots of 16 lanes
  int node = blockIdx.x*16 + slot;
  int c = threadIdx.x & 15;
  int rs = rowptr[(size_t)z*(N+1) + node];
  int re = rowptr[(size_t)z*(N+1) + node + 1];
  unsigned xru = xr23p[((size_t)z*N + node)*CH + c];
  float xr2v = unpl(xru), xr3v = unph(xru);   // (conv2, skip-conv)
  unsigned w2p[8], w3p[8];
  #pragma unroll
  for (int jp=0;jp<8;jp++){
    w2p[jp] = packh2(ldv(We2,(size_t)(2*jp)*CH+c), ldv(We2,(size_t)(2*jp+1)*CH+c));
    w3p[jp] = packh2(ldv(We3,(size_t)(2*jp)*CH+c), ldv(We3,(size_t)(2*jp+1)*CH+c));
  }
  float att2c = ldv(att2,(size_t)c)*L2E, att3c = ldv(att3,(size_t)c)*L2E;
  float acc2=0.f, acc3=0.f, den2=0.f, den3=0.f;
  const unsigned* __restrict__ xlp = xl23p + (size_t)z*N*CH;
  const int* __restrict__ csrz = csr + (size_t)z*E;

  auto edge = [&](int i, unsigned xw){
    float xl2v = unpl(xw), xl3v = unph(xw);
    uint4 q0 = *(const uint4*)&eas[slot][i][0];
    uint4 q1 = *(const uint4*)&eas[slot][i][4];
    float g2 = xl2v + xr2v, g3 = xl3v + xr3v;
    g2 = dot2(q0.x, w2p[0], g2);  g3 = dot2(q0.x, w3p[0], g3);
    g2 = dot2(q0.y, w2p[1], g2);  g3 = dot2(q0.y, w3p[1], g3);
    g2 = dot2(q0.z, w2p[2], g2);  g3 = dot2(q0.z, w3p[2], g3);
    g2 = dot2(q0.w, w2p[3], g2);  g3 = dot2(q0.w, w3p[3], g3);
    g2 = dot2(q1.x, w2p[4], g2);  g3 = dot2(q1.x, w3p[4], g3);
    g2 = dot2(q1.y, w2p[5], g2);  g3 = dot2(q1.y, w3p[5], g3);
    g2 = dot2(q1.z, w2p[6], g2);  g3 = dot2(q1.z, w3p[6], g3);
    g2 = dot2(q1.w, w2p[7], g2);  g3 = dot2(q1.w, w3p[7], g3);
    float v2 = rsum16(leaky(g2)*att2c);
    float v3 = rsum16(leaky(g3)*att3c);
    float ex2 = exp2f(clampf(v2,-86.f,86.f));
    float ex3 = exp2f(clampf(v3,-86.f,86.f));
    den2 += ex2; den3 += ex3;
    acc2 = fmaf(ex2, xl2v, acc2);
    acc3 = fmaf(ex3, xl3v, acc3);
  };

  for (int base = rs; base < re; base += TB2){
    int m = re - base; if (m > TB2) m = TB2;
    if (c < m) ssrc[slot][c] = csrz[base + c];
    const uint4* ep = (const uint4*)(ea8 + ((size_t)z*E + base)*8);
    for (int i4=c; i4<m*2; i4+=16)
      ((uint4*)eas[slot])[i4] = ep[i4];
    unsigned pa = xlp[(unsigned)(ssrc[slot][0]*CH + c)];
    unsigned pb = (m>1) ? xlp[(unsigned)(ssrc[slot][1]*CH + c)] : pa;
    int i = 0;
    for (; i+1 < m; i += 2){
      unsigned x0 = pa, x1 = pb;
      int i2 = (i+2 < m) ? i+2 : m-1;
      int i3 = (i+3 < m) ? i+3 : m-1;
      int s2 = ssrc[slot][i2], s3 = ssrc[slot][i3];
      pa = xlp[(unsigned)(s2*CH + c)];
      pb = xlp[(unsigned)(s3*CH + c)];
      edge(i, x0);
      edge(i+1, x1);
    }
    if (i < m) edge(i, pa);
  }
  float x1 = acc2/(den2 + 1e-16f) + ldv(b2,(size_t)c);   // conv2 output
  float x3 = acc3/(den3 + 1e-16f) + ldv(b3,(size_t)c);   // skip-conv output
  float x2 = 0.f;
  #pragma unroll
  for (int j=0;j<16;j++) x2 += __shfl(x3, j, 16) * ldv(linW, (size_t)c*16 + j);
  x2 += ldv(linb,(size_t)c);
  float y = clampf(x1, -1e6f, 1e6f) + clampf(x2, -1e6f, 1e6f);
  float mu = rsum16(y)*(1.f/16.f);
  float dv = y - mu;
  float var = rsum16(dv*dv)*(1.f/16.f);
  float o = dv*rsqrtf(var + 1e-5f)*ldv(lng,(size_t)c) + ldv(lnb,(size_t)c);
  stv(out, ((size_t)(b0+z)*N + node)*16 + c, o);
}
__global__ __launch_bounds__(256) void k_gather23(const int* __restrict__ rowptr, const int* __restrict__ csr,
    const unsigned* __restrict__ ea8,
    const void* We2, const void* We3, const void* att2, const void* att3,
    const void* b2, const void* b3, const void* linW, const void* linb, const void* lng, const void* lnb,
    const unsigned* __restrict__ xl23p, const unsigned* __restrict__ xr23p,
    void* out, const int* __restrict__ flag, int b0){
  __shared__ int ssrc[16][TB2];
  __shared__ unsigned eas[16][TB2][8];
  if (*flag) gather23_body(rowptr,csr,ea8,(const float*)We2,(const float*)We3,(const float*)att2,(const float*)att3,
                           (const float*)b2,(const float*)b3,(const float*)linW,(const float*)linb,(const float*)lng,(const float*)lnb,
                           xl23p,xr23p,(float*)out,b0,ssrc,eas);
  else       gather23_body(rowptr,csr,ea8,(const bf16*) We2,(const bf16*) We3,(const bf16*) att2,(const bf16*) att3,
                           (const bf16*) b2,(const bf16*) b3,(const bf16*) linW,(const bf16*) linb,(const bf16*) lng,(const bf16*) lnb,
                           xl23p,xr23p,(bf16*) out,b0,ssrc,eas);
}

// ---------------- workspace layout ----------------
struct WSP {
  int* flag;
  int *cnt, *cursor, *rowptr; int* csr;
  unsigned* ea8;
  float* hx;
  unsigned *xl1p,*xr1p,*xl23p,*xr23p;
  size_t total;
};
static WSP mkws(char* base, int nb){
  WSP w; size_t off = 0;
  auto A = [&](size_t bytes)->char*{ char* p = base ? base + off : (char*)0; off = (off + bytes + 255) & ~(size_t)255; return p; };
  w.flag   = (int*)     A(256);
  w.cnt    = (int*)     A((size_t)nb*N*4);
  w.cursor = (int*)     A((size_t)nb*N*4);
  w.rowptr = (int*)     A((size_t)nb*(N+1)*4);
  w.csr    = (int*)     A((size_t)nb*E*4);
  w.ea8    = (unsigned*)A((size_t)nb*E*8*4);
  w.hx     = (float*)   A((size_t)nb*N*HC*4);
  w.xl1p   = (unsigned*)A((size_t)nb*N*64*4);
  w.xr1p   = (unsigned*)A((size_t)nb*N*64*4);
  w.xl23p  = (unsigned*)A((size_t)nb*N*CH*4);
  w.xr23p  = (unsigned*)A((size_t)nb*N*CH*4);
  w.total = off;
  return w;
}

extern "C" void kernel_launch(void* const* d_in, const int* in_sizes, int n_in,
                              void* d_out, int out_size, void* d_ws, size_t ws_size,
                              hipStream_t stream){
  const void* x    = d_in[0];
  const void* ea   = d_in[1];
  const int*  ei   = (const int*)d_in[2];
  const void* c1Wl = d_in[3], *c1Wr = d_in[4], *c1We = d_in[5];
  const void* c1att= d_in[6], *c1b  = d_in[7];
  const void* c2Wl = d_in[8], *c2Wr = d_in[9], *c2We = d_in[10];
  const void* c2att= d_in[11],*c2b  = d_in[12];
  const void* sWl  = d_in[13],*sWr  = d_in[14],*sWe  = d_in[15];
  const void* satt = d_in[16],*sb   = d_in[17];
  const void* linW = d_in[18],*linb = d_in[19];
  const void* lng  = d_in[20],*lnb  = d_in[21];

  auto run = [&](int b0, int nb){
    WSP w = mkws((char*)d_ws, nb);
    hipMemsetAsync(w.cnt, 0, (size_t)nb*N*4, stream);
    k_hist   <<<dim3(E/256,1,nb),   256,0,stream>>>(ei, w.cnt, b0);
    k_scan   <<<dim3(1,1,nb),       256,0,stream>>>(w.cnt, w.rowptr, w.cursor);
    k_scatter<<<dim3(E/256,1,nb),   256,0,stream>>>(ei, w.cursor, w.csr, ea, w.ea8, w.flag, b0);
    // conv1
    k_node1  <<<dim3(N/NT,1,nb),    256,0,stream>>>(x, c1Wl, c1Wr, w.xl1p, w.xr1p, w.flag, b0);
    k_gather1<<<dim3(N/4,1,nb),     256,0,stream>>>(w.rowptr, w.csr, w.ea8, c1We, c1att, c1b,
                                                    w.xl1p, w.xr1p, w.hx, w.flag, b0);
    // conv2 + skip-conv
    k_node2  <<<dim3(N/NT,1,nb),    256,0,stream>>>(w.hx, w.xl1p, c2Wl, c2Wr, sWl, sWr,
                                                    w.xl23p, w.xr23p, w.flag, b0);
    k_gather23<<<dim3(N/16,1,nb),   256,0,stream>>>(w.rowptr, w.csr, w.ea8, c2We, sWe, c2att, satt,
                                                    c2b, sb, linW, linb, lng, lnb,
                                                    w.xl23p, w.xr23p, d_out, w.flag, b0);
  };

  {
    WSP w0 = mkws((char*)d_ws, 1);
    k_detect<<<1,256,0,stream>>>((const unsigned short*)x, w0.flag);
  }

  WSP probe = mkws((char*)0, NB_B);
  if (ws_size >= probe.total){
    run(0, NB_B);                          // single batched pass
  } else {
    for (int g=0; g<NB_B; ++g) run(g, 1);  // per-graph fallback
  }
}